// Round 8
// baseline (148.667 us; speedup 1.0000x reference)
//
#include <hip/hip_runtime.h>

#define IMG_H 480
#define IMG_W 640
#define OUT_H 470    // 480 - 10
#define OUT_W 630    // 640 - 10
#define NBATCH 32
#define SW 126       // output columns per wave (63 lanes x 2); 5*126 = 630 exact
#define NSTRIPE 5
#define RCH 24       // output rows per wave-chunk (24*20 = 480 >= 470, tail masked)
#define NCHUNK 20
#define NROWS (RCH + 10)   // 34 input rows per chunk
#define TD 6         // touch distance in rows (~6 steps of lead >> HBM latency)

#define SSIM_C1 1.0f // (0.01*100)^2
#define SSIM_C2 9.0f // (0.03*100)^2

typedef float v2f __attribute__((ext_vector_type(2)));

// Normalized 11-tap Gaussian (sigma=1.5), matches numpy fp32 window to ~1e-7 rel.
__device__ constexpr float WG[11] = {
    0.00102838f, 0.00759876f, 0.03600077f, 0.10936068f, 0.21300554f,
    0.26601173f,
    0.21300554f, 0.10936068f, 0.03600077f, 0.00759876f, 0.00102838f
};

// Packed fp32 fma: llvm.fma.v2f32 -> v_pk_fma_f32
__device__ __forceinline__ v2f pk_fma(v2f a, v2f b, v2f c) {
    return __builtin_elementwise_fma(a, b, c);
}

// R8 TOUCH: volatile asm global_load whose result is chained but never
// consumed through the scoreboard.
//  - volatile => not DCE-able (R7 lesson: plain loads into a rotating sink
//    are dead stores; ALL in-loop touches were deleted -- FETCH +7MB and
//    VGPR +4 showed only the prologue touches survived).
//  - "+v"(junk) => junk's live range spans the whole loop, its VGPR is
//    never re-allocated, so an in-flight touch can never land in a register
//    the allocator gave to live data (WAW garbage into junk is harmless).
//  - no read of the result => compiler emits no s_waitcnt for touches.
//    Its counted vmcnt(N) for demand loads under-counts by the hidden
//    touches, so each step's wait also retires ~2 of the NEXT row's demand
//    loads -- those were touched TD rows earlier => ~L2-hit latency, cheap.
#define TOUCH(addr)                                                           \
  asm volatile("global_load_dword %0, %1, off"                                \
               : "+v"(junk) : "v"(addr))

// HISTORY (R1-R7): all structural variants pinned at ~1300-1500 cyc/step vs
// ~560 cyc issue, VALUBusy ~43%. FETCH_SIZE == input size => every demand
// load is a compulsory HBM miss (~900 cyc); at ~1.2 waves/SIMD residency
// nothing covers it. R4 (VGPR prefetch depth) pinned by reg reuse; R6
// (LDS-DMA) died on lgkmcnt coupling; R7 touches were DCE'd. R8 = touches
// that provably emit.
// *** INDEXING MUST BE COMPILE-TIME *** PP is a post-unroll literal
// (22-step unroll: 22 ≡ 0 mod 11, even). IT literal here (straight-line).
// Sentinels: VGPR ~115, WRITE_SIZE ~100 KB (R2: spill = 118MB), FETCH
// ~82 MB (touches add no new lines), absmax 0.
#define STEP(IT, PP)                                                          \
  {                                                                           \
    const int P   = (PP) % 11;                                                \
    const int cur = (PP) & 1;                                                 \
    const int nxt = ((PP) + 1) & 1;                                           \
    /* 1. demand prefetch row IT+1 into pb[nxt] (clamped; overshoot ok) */    \
    {                                                                         \
      int gy = y0 + (IT) + 1; if (gy > IMG_H - 1) gy = IMG_H - 1;             \
      const float* __restrict__ r1 = p1 + gy * IMG_W + colA;                  \
      const float* __restrict__ r2 = p2 + gy * IMG_W + colA;                  \
      _Pragma("unroll")                                                       \
      for (int k = 0; k < 6; ++k) {                                           \
        pb[nxt][0][k] = *(const v2f*)(r1 + 2 * k);                            \
        pb[nxt][1][k] = *(const v2f*)(r2 + 2 * k);                            \
      }                                                                       \
    }                                                                         \
    /* 1b. touch row IT+TD (AFTER demand loads: the compiler's blind        */\
    /*     vmcnt(N) then waits on warmed next-row demands, never on a       */\
    /*     fresh touch). Volatile asm: emitted, in order, no waitcnt.       */\
    if ((IT) + TD <= NROWS + 1) {                                             \
      int gty = y0 + (IT) + TD; if (gty > IMG_H - 1) gty = IMG_H - 1;         \
      TOUCH(p1 + gty * IMG_W + tcol);                                         \
      TOUCH(p2 + gty * IMG_W + tcol);                                         \
    }                                                                         \
    /* 2. h-pass on pb[cur] (row IT), packed over output cols (A,B) */        \
    v2f h1  = (v2f){0.f,0.f}, h2  = (v2f){0.f,0.f};                           \
    v2f h11 = (v2f){0.f,0.f}, h22 = (v2f){0.f,0.f}, h12 = (v2f){0.f,0.f};     \
    _Pragma("unroll")                                                         \
    for (int j = 0; j < 11; ++j) {                                            \
      const v2f wj = (v2f){WG[j], WG[j]};                                     \
      v2f q1, q2;                                                             \
      if (j & 1) {                                                            \
        q1 = (v2f){pb[cur][0][j >> 1].y, pb[cur][0][(j >> 1) + 1].x};         \
        q2 = (v2f){pb[cur][1][j >> 1].y, pb[cur][1][(j >> 1) + 1].x};         \
      } else {                                                                \
        q1 = pb[cur][0][j >> 1];                                              \
        q2 = pb[cur][1][j >> 1];                                              \
      }                                                                       \
      const v2f t1 = wj * q1;                                                 \
      const v2f t2 = wj * q2;                                                 \
      h1 += t1; h2 += t2;                                                     \
      h11 = pk_fma(t1, q1, h11);                                              \
      h22 = pk_fma(t2, q2, h22);                                              \
      h12 = pk_fma(t1, q2, h12);                                              \
    }                                                                         \
    /* 3. vertical ring update: 5 pk_fma per slot */                          \
    _Pragma("unroll")                                                         \
    for (int sl = 0; sl < 11; ++sl) {                                         \
      const float wt = WG[(P - sl + 11) % 11];                                \
      const v2f wv = (v2f){wt, wt};                                           \
      acc[sl][0] = pk_fma(wv, h1,  acc[sl][0]);                               \
      acc[sl][1] = pk_fma(wv, h2,  acc[sl][1]);                               \
      acc[sl][2] = pk_fma(wv, h11, acc[sl][2]);                               \
      acc[sl][3] = pk_fma(wv, h22, acc[sl][3]);                               \
      acc[sl][4] = pk_fma(wv, h12, acc[sl][4]);                               \
    }                                                                         \
    /* 4. slot sc got its w[10] tap -> output row y = IT-10 completes */      \
    const int sc = (P + 1) % 11;                                              \
    if ((IT) >= 10 && (y0 + (IT) - 10) < OUT_H) {                             \
      const v2f m1 = acc[sc][0], m2 = acc[sc][1];                             \
      const v2f msq1 = m1 * m1, msq2 = m2 * m2, mu12 = m1 * m2;               \
      const v2f two = (v2f){2.f, 2.f};                                        \
      const v2f c1v = (v2f){SSIM_C1, SSIM_C1};                                \
      const v2f c2v = (v2f){SSIM_C2, SSIM_C2};                                \
      const v2f vA = pk_fma(two, acc[sc][4] - mu12, c2v);                     \
      const v2f vB = (acc[sc][2] - msq1) + (acc[sc][3] - msq2) + c2v;         \
      const v2f num = pk_fma(two, mu12, c1v) * vA;                            \
      const v2f den = (msq1 + msq2 + c1v) * vB;                               \
      if (validA) lsum = fmaf(num.x, __builtin_amdgcn_rcpf(den.x), lsum);     \
      if (validB) lsum = fmaf(num.y, __builtin_amdgcn_rcpf(den.y), lsum);     \
    }                                                                         \
    _Pragma("unroll")                                                         \
    for (int ch = 0; ch < 5; ++ch) acc[sc][ch] = (v2f){0.f, 0.f};             \
  }

__global__ __launch_bounds__(64, 2) void ssim_main(
    const float* __restrict__ img1,
    const float* __restrict__ img2,
    float* __restrict__ partials)
{
    const int lane   = threadIdx.x;
    const int stripe = blockIdx.x;
    const int cy     = blockIdx.y;
    const int b      = blockIdx.z;
    const int x0 = SW * stripe;
    const int y0 = RCH * cy;

    const float* __restrict__ p1 = img1 + (size_t)b * (IMG_H * IMG_W);
    const float* __restrict__ p2 = img2 + (size_t)b * (IMG_H * IMG_W);

    // lane's 12-col demand window base (clamped; no-op for valid lanes)
    int colA = x0 + 2 * lane;
    if (colA > IMG_W - 12) colA = IMG_W - 12;   // 628, even -> 8B aligned

    // touch column: stride 3 dwords (12B < 128B line) -> every line of
    // [x0, x0+137] touched; clamped in-bounds.
    int tcol = x0 + 3 * lane;
    {
        int tmax = x0 + 137; if (tmax > IMG_W - 1) tmax = IMG_W - 1;
        if (tcol > tmax) tcol = tmax;
    }

    // lane l produces output cols x0+2l (A) and x0+2l+1 (B); lanes 0..62 valid
    const bool validA = (2 * lane     < SW) && (x0 + 2 * lane     < OUT_W);
    const bool validB = (2 * lane + 1 < SW) && (x0 + 2 * lane + 1 < OUT_W);

    // vertical ring: 5 channels (mu1, mu2, s11, s22, s12), each v2f over (A,B)
    v2f acc[11][5];
#pragma unroll
    for (int i = 0; i < 11; ++i)
#pragma unroll
        for (int ch = 0; ch < 5; ++ch) acc[i][ch] = (v2f){0.f, 0.f};

    float lsum = 0.f;

    // touch sink: chained through every TOUCH -> one permanently-held VGPR
    float junk = 0.f;

    // prologue touches: rows y0+1 .. y0+TD-1 (row y0 is demand-loaded next).
    // Issued FIRST: longest-latency pole; steady state from step ~TD-1 has
    // full TD-step lead.
#pragma unroll
    for (int r = 1; r < TD; ++r) {
        TOUCH(p1 + (y0 + r) * IMG_W + tcol);
        TOUCH(p2 + (y0 + r) * IMG_W + tcol);
    }

    // input-row ping-pong: pb[parity][image][pair 0..5]
    v2f pb[2][2][6];

    // prologue: demand row y0 -> pb[0]
    {
        const float* __restrict__ r1 = p1 + y0 * IMG_W + colA;
        const float* __restrict__ r2 = p2 + y0 * IMG_W + colA;
#pragma unroll
        for (int k = 0; k < 6; ++k) {
            pb[0][0][k] = *(const v2f*)(r1 + 2 * k);
            pb[0][1][k] = *(const v2f*)(r2 + 2 * k);
        }
    }

    // 34 rows: 22-step literal unroll + 12-step literal tail (proven shape)
#pragma unroll
    for (int p = 0; p < 22; ++p) STEP(p, p)
#pragma unroll
    for (int p = 0; p < 12; ++p) STEP(22 + p, p)

    // final sink keeps the junk chain rooted (belt-and-suspenders; the
    // volatile asms above are already non-deletable)
    asm volatile("" :: "v"(junk));

    // wave-level reduction (64 lanes)
#pragma unroll
    for (int off = 32; off > 0; off >>= 1)
        lsum += __shfl_down(lsum, off);
    if (lane == 0)
        partials[(b * NCHUNK + cy) * NSTRIPE + stripe] = lsum;
}

__global__ __launch_bounds__(256) void ssim_reduce(
    const float* __restrict__ partials, float* __restrict__ out)
{
    const int n = NSTRIPE * NCHUNK * NBATCH;  // 3200
    __shared__ double red[256];
    int tid = threadIdx.x;
    double s = 0.0;
    for (int i = tid; i < n; i += 256) s += (double)partials[i];
    red[tid] = s;
    __syncthreads();
    for (int k = 128; k > 0; k >>= 1) {
        if (tid < k) red[tid] += red[tid + k];
        __syncthreads();
    }
    if (tid == 0) {
        double mean = red[0] / (double)((size_t)NBATCH * OUT_H * OUT_W);
        out[0] = (float)((1.0 - mean) * 0.5);
    }
}

extern "C" void kernel_launch(void* const* d_in, const int* in_sizes, int n_in,
                              void* d_out, int out_size, void* d_ws, size_t ws_size,
                              hipStream_t stream)
{
    const float* img1 = (const float*)d_in[0];
    const float* img2 = (const float*)d_in[1];
    float* out = (float*)d_out;
    float* partials = (float*)d_ws;  // 3200 floats = 12.8 KB

    dim3 grid(NSTRIPE, NCHUNK, NBATCH);  // 5 x 20 x 32 = 3200 single-wave blocks
    ssim_main<<<grid, dim3(64), 0, stream>>>(img1, img2, partials);
    ssim_reduce<<<1, dim3(256), 0, stream>>>(partials, out);
}

// Round 9
// 147.675 us; speedup vs baseline: 1.0067x; 1.0067x over previous
//
#include <hip/hip_runtime.h>

#define IMG_H 480
#define IMG_W 640
#define OUT_H 470    // 480 - 10
#define OUT_W 630    // 640 - 10
#define NBATCH 32
#define SW 126       // output columns per wave (63 lanes x 2); 5*126 = 630 exact
#define NSTRIPE 5
#define RCH 24       // output rows per wave-chunk (24*20 = 480 >= 470, tail masked)
#define NCHUNK 20
#define NROWS (RCH + 10)   // 34 input rows per chunk = 17 two-row steps

#define SSIM_C1 1.0f // (0.01*100)^2
#define SSIM_C2 9.0f // (0.03*100)^2

typedef float v2f __attribute__((ext_vector_type(2)));

// Normalized 11-tap Gaussian (sigma=1.5), matches numpy fp32 window to ~1e-7 rel.
__device__ constexpr float WG[11] = {
    0.00102838f, 0.00759876f, 0.03600077f, 0.10936068f, 0.21300554f,
    0.26601173f,
    0.21300554f, 0.10936068f, 0.03600077f, 0.00759876f, 0.00102838f
};

// Packed fp32 fma: llvm.fma.v2f32 -> v_pk_fma_f32
__device__ __forceinline__ v2f pk_fma(v2f a, v2f b, v2f c) {
    return __builtin_elementwise_fma(a, b, c);
}

// HISTORY (R1-R8): every latency-HIDING mechanism failed on the same ~57us /
// VALUBusy 43% floor: VGPR prefetch depth (R4, reg-reuse pins the wait),
// LDS-DMA counted vmcnt (R6, global_load_lds shares lgkmcnt with ds_read ->
// full drain each step, 133us), L2-warming touches (R8, volatile-asm fence
// + vmcnt queue inflation, 71us). Model: each step = ~560 cyc issue + one
// ~900 cyc scoreboard wait on the row's compulsory-miss loads; at ~1.5
// waves/SIMD nothing covers it. R9: AMORTIZE instead of hide -- process 2
// rows per step, prefetch 2 rows per step. One wait per TWO rows; the 1120
// cyc of paired compute also covers most of the next pair's flight time.
// REGISTER BUDGET: pb doubles to 96 regs; acc 110; working ~35 -> ~240.
// __launch_bounds__(64,1) -> 512-reg cap (no spill); HW still allows 2
// waves/SIMD at <=256 VGPR (occupancy steps at 64/128/256, m69).
// *** INDEXING MUST BE COMPILE-TIME *** SS is a post-unroll literal
// (straight-line 17 steps); phases (2S)%11, (2S+1)%11, parity S&1 all fold.
// Sentinels: VGPR 230-256 (>256 or WRITE_SIZE in MB = spill -> R2 mode),
// WRITE_SIZE ~100 KB, FETCH ~75 MB, absmax 0.

// Process one row from pb[CUR][R]: h-pass -> ring update at phase P ->
// epilogue for completed output row (ITR-10) -> clear recycled slot.
#define ROWP(ITR, P, CUR, R)                                                  \
  {                                                                           \
    v2f h1  = (v2f){0.f,0.f}, h2  = (v2f){0.f,0.f};                           \
    v2f h11 = (v2f){0.f,0.f}, h22 = (v2f){0.f,0.f}, h12 = (v2f){0.f,0.f};     \
    _Pragma("unroll")                                                         \
    for (int j = 0; j < 11; ++j) {                                            \
      const v2f wj = (v2f){WG[j], WG[j]};                                     \
      v2f q1, q2;                                                             \
      if (j & 1) {                                                            \
        q1 = (v2f){pb[CUR][R][0][j >> 1].y, pb[CUR][R][0][(j >> 1) + 1].x};   \
        q2 = (v2f){pb[CUR][R][1][j >> 1].y, pb[CUR][R][1][(j >> 1) + 1].x};   \
      } else {                                                                \
        q1 = pb[CUR][R][0][j >> 1];                                           \
        q2 = pb[CUR][R][1][j >> 1];                                           \
      }                                                                       \
      const v2f t1 = wj * q1;                                                 \
      const v2f t2 = wj * q2;                                                 \
      h1 += t1; h2 += t2;                                                     \
      h11 = pk_fma(t1, q1, h11);                                              \
      h22 = pk_fma(t2, q2, h22);                                              \
      h12 = pk_fma(t1, q2, h12);                                              \
    }                                                                         \
    _Pragma("unroll")                                                         \
    for (int sl = 0; sl < 11; ++sl) {                                         \
      const float wt = WG[((P) - sl + 11) % 11];                              \
      const v2f wv = (v2f){wt, wt};                                           \
      acc[sl][0] = pk_fma(wv, h1,  acc[sl][0]);                               \
      acc[sl][1] = pk_fma(wv, h2,  acc[sl][1]);                               \
      acc[sl][2] = pk_fma(wv, h11, acc[sl][2]);                               \
      acc[sl][3] = pk_fma(wv, h22, acc[sl][3]);                               \
      acc[sl][4] = pk_fma(wv, h12, acc[sl][4]);                               \
    }                                                                         \
    const int sc = ((P) + 1) % 11;                                            \
    if ((ITR) >= 10 && (y0 + (ITR) - 10) < OUT_H) {                           \
      const v2f m1 = acc[sc][0], m2 = acc[sc][1];                             \
      const v2f msq1 = m1 * m1, msq2 = m2 * m2, mu12 = m1 * m2;               \
      const v2f two = (v2f){2.f, 2.f};                                        \
      const v2f c1v = (v2f){SSIM_C1, SSIM_C1};                                \
      const v2f c2v = (v2f){SSIM_C2, SSIM_C2};                                \
      const v2f vA = pk_fma(two, acc[sc][4] - mu12, c2v);                     \
      const v2f vB = (acc[sc][2] - msq1) + (acc[sc][3] - msq2) + c2v;         \
      const v2f num = pk_fma(two, mu12, c1v) * vA;                            \
      const v2f den = (msq1 + msq2 + c1v) * vB;                               \
      if (validA) lsum = fmaf(num.x, __builtin_amdgcn_rcpf(den.x), lsum);     \
      if (validB) lsum = fmaf(num.y, __builtin_amdgcn_rcpf(den.y), lsum);     \
    }                                                                         \
    _Pragma("unroll")                                                         \
    for (int ch = 0; ch < 5; ++ch) acc[sc][ch] = (v2f){0.f, 0.f};             \
  }

// One pair-step SS (literal): prefetch rows 2*SS+2, 2*SS+3 into pb[nxt],
// then process rows 2*SS and 2*SS+1 from pb[cur]. One scoreboard wait per
// TWO rows. Last step's prefetch (rows 36,37 clamped) is dead -> DCE'd.
#define STEP2(SS)                                                             \
  {                                                                           \
    const int cur = (SS) & 1;                                                 \
    const int nxt = cur ^ 1;                                                  \
    _Pragma("unroll")                                                         \
    for (int r = 0; r < 2; ++r) {                                             \
      int gy = y0 + 2 * (SS) + 2 + r;                                         \
      if (gy > IMG_H - 1) gy = IMG_H - 1;                                     \
      const float* __restrict__ rr1 = p1 + gy * IMG_W + colA;                 \
      const float* __restrict__ rr2 = p2 + gy * IMG_W + colA;                 \
      _Pragma("unroll")                                                       \
      for (int k = 0; k < 6; ++k) {                                           \
        pb[nxt][r][0][k] = *(const v2f*)(rr1 + 2 * k);                        \
        pb[nxt][r][1][k] = *(const v2f*)(rr2 + 2 * k);                        \
      }                                                                       \
    }                                                                         \
    ROWP(2 * (SS),     (2 * (SS)) % 11,     cur, 0)                           \
    ROWP(2 * (SS) + 1, (2 * (SS) + 1) % 11, cur, 1)                           \
  }

__global__ __launch_bounds__(64, 1) void ssim_main(
    const float* __restrict__ img1,
    const float* __restrict__ img2,
    float* __restrict__ partials)
{
    const int lane   = threadIdx.x;
    const int stripe = blockIdx.x;
    const int cy     = blockIdx.y;
    const int b      = blockIdx.z;
    const int x0 = SW * stripe;
    const int y0 = RCH * cy;

    const float* __restrict__ p1 = img1 + (size_t)b * (IMG_H * IMG_W);
    const float* __restrict__ p2 = img2 + (size_t)b * (IMG_H * IMG_W);

    // lane's 12-col window base (clamped; no-op for valid lanes)
    int colA = x0 + 2 * lane;
    if (colA > IMG_W - 12) colA = IMG_W - 12;   // 628, even -> 8B aligned

    // lane l produces output cols x0+2l (A) and x0+2l+1 (B); lanes 0..62 valid
    const bool validA = (2 * lane     < SW) && (x0 + 2 * lane     < OUT_W);
    const bool validB = (2 * lane + 1 < SW) && (x0 + 2 * lane + 1 < OUT_W);

    // vertical ring: 5 channels (mu1, mu2, s11, s22, s12), each v2f over (A,B)
    v2f acc[11][5];
#pragma unroll
    for (int i = 0; i < 11; ++i)
#pragma unroll
        for (int ch = 0; ch < 5; ++ch) acc[i][ch] = (v2f){0.f, 0.f};

    float lsum = 0.f;

    // row-pair ping-pong: pb[parity][row-in-pair][image][pair 0..5]
    v2f pb[2][2][2][6];

    // prologue: rows y0, y0+1 -> pb[0][0], pb[0][1] (y0+1 <= 457, in bounds)
#pragma unroll
    for (int r = 0; r < 2; ++r) {
        const float* __restrict__ r1 = p1 + (y0 + r) * IMG_W + colA;
        const float* __restrict__ r2 = p2 + (y0 + r) * IMG_W + colA;
#pragma unroll
        for (int k = 0; k < 6; ++k) {
            pb[0][r][0][k] = *(const v2f*)(r1 + 2 * k);
            pb[0][r][1][k] = *(const v2f*)(r2 + 2 * k);
        }
    }

    // 34 rows = 17 straight-line pair-steps, all indices literal
#pragma unroll
    for (int s = 0; s < 17; ++s) STEP2(s)

    // wave-level reduction (64 lanes)
#pragma unroll
    for (int off = 32; off > 0; off >>= 1)
        lsum += __shfl_down(lsum, off);
    if (lane == 0)
        partials[(b * NCHUNK + cy) * NSTRIPE + stripe] = lsum;
}

__global__ __launch_bounds__(256) void ssim_reduce(
    const float* __restrict__ partials, float* __restrict__ out)
{
    const int n = NSTRIPE * NCHUNK * NBATCH;  // 3200
    __shared__ double red[256];
    int tid = threadIdx.x;
    double s = 0.0;
    for (int i = tid; i < n; i += 256) s += (double)partials[i];
    red[tid] = s;
    __syncthreads();
    for (int k = 128; k > 0; k >>= 1) {
        if (tid < k) red[tid] += red[tid + k];
        __syncthreads();
    }
    if (tid == 0) {
        double mean = red[0] / (double)((size_t)NBATCH * OUT_H * OUT_W);
        out[0] = (float)((1.0 - mean) * 0.5);
    }
}

extern "C" void kernel_launch(void* const* d_in, const int* in_sizes, int n_in,
                              void* d_out, int out_size, void* d_ws, size_t ws_size,
                              hipStream_t stream)
{
    const float* img1 = (const float*)d_in[0];
    const float* img2 = (const float*)d_in[1];
    float* out = (float*)d_out;
    float* partials = (float*)d_ws;  // 3200 floats = 12.8 KB

    dim3 grid(NSTRIPE, NCHUNK, NBATCH);  // 5 x 20 x 32 = 3200 single-wave blocks
    ssim_main<<<grid, dim3(64), 0, stream>>>(img1, img2, partials);
    ssim_reduce<<<1, dim3(256), 0, stream>>>(partials, out);
}